// Round 11
// baseline (96.159 us; speedup 1.0000x reference)
//
#include <hip/hip_runtime.h>
#include <math.h>

#define NXv 128
#define NYv 128
#define NZv 128
#define NVOX (NXv * NYv * NZv)
#define RPB  64    // rays per block (lane = ray in compute phase)
#define TSEG 63    // segments per LDS tile (loads TSEG+1 = 64 t-values/ray)

// Lane-per-ray tiled kernel + reg-prefetch pipeline + 4-wide gather batches.
//  * tvals bits are AUTHORITATIVE: R6 proved on-the-fly recompute differs at
//    the ulp level (XLA divide != HW IEEE div bits) and flips knife-edge
//    floors. tvals must be read from memory.
//  * lane = ray (R7, 142->93us): adjacent rays differ only in detector v ->
//    volume gathers span few cache lines instead of 64 (R4/R5 floor).
//  * tvals coalescing via LDS transpose tile, stride 65 -> conflict-free.
//  * reg-prefetch of next tile before compute (R8, 93->84us).
//  * R9 FAILED (133us): 16-wide batch + launch_bounds(256,4) VGPR cap ->
//    scratch spill (WRITE_SIZE 1->56MB). R10 FAILED (91us): balanced ray
//    remap didn't raise occupancy (imbalance exonerated) and hurt gather
//    clustering. R11: 4-wide batches (phase-split within group: 4 offsets ->
//    8 predicated gathers back-to-back -> 4x2 fma), no VGPR cap. R8's
//    VALUBusy 21% at full residency = gather ILP ~1-2 per wave; 8 loads in
//    flight per wave is the lever.
//
// NUMERICS (hard-won, rounds 1-10): x-segment midpoints land EXACTLY on
// floor() discontinuities. Golden ref is f32 numpy, SEPARATE mul-then-add.
// hipcc contracts a+tm*d into FMA -> absmax ~18.7 (threshold 1.25); __f*_rn
// are contractible (R2 == R1 bitwise); f64 mismatches (R3); recomputed t
// mismatches (R6). The asm VGPR pin on the product tm*d is what works
// (R4/R5/R7/R8/R10 passed, absmax 0.0625). Do not remove. Keep contract(off).
// Invalid lanes: clamp float BEFORE int cast (inf/NaN -> well-defined),
// clamp flat index, force weight 0 -> adding +0 is bit-neutral (proven R5).
template <int BT>
__global__ __launch_bounds__(256) void ct_ilp(
    const float* __restrict__ vol,    // (B, NX, NY, NZ)
    const float* __restrict__ tvals,  // (R, S) sorted, +inf padded
    const float* __restrict__ Mm,     // (3,3)
    const float* __restrict__ bb,     // (3,)
    const float* __restrict__ src,    // (R,3)
    const float* __restrict__ dst,    // (R,3)
    float* __restrict__ out,          // (B, R)
    int R, int S)
{
#pragma clang fp contract(off)
    __shared__ float tile[RPB][TSEG + 2];   // 64 x 65: stride 65 -> conflict-free
    __shared__ float red[4][RPB][2];        // cross-sub reduction

    const float INF = __builtin_inff();
    const int t   = threadIdx.x;
    const int rr  = t & 63;        // compute role: ray within block
    const int sub = t >> 6;        // compute role: segment sub-range 0..3
    const int r0  = blockIdx.x * RPB;
    const int r   = r0 + rr;
    const bool active = (r < R);

    // --- per-ray geometry (verified R4/R5/R7/R8) ---
    float ax = 0, ay = 0, az = 0, dxx = 0, dyy = 0, dzz = 0, raylen = 0;
    if (active) {
        const float sx = src[r * 3 + 0], sy = src[r * 3 + 1], sz = src[r * 3 + 2];
        const float ex = dst[r * 3 + 0], ey = dst[r * 3 + 1], ez = dst[r * 3 + 2];
        const float M00 = Mm[0], M01 = Mm[1], M02 = Mm[2];
        const float M10 = Mm[3], M11 = Mm[4], M12 = Mm[5];
        const float M20 = Mm[6], M21 = Mm[7], M22 = Mm[8];
        ax = M00 * sx + M01 * sy + M02 * sz + bb[0];
        ay = M10 * sx + M11 * sy + M12 * sz + bb[1];
        az = M20 * sx + M21 * sy + M22 * sz + bb[2];
        const float vx = ex - sx, vy = ey - sy, vz = ez - sz;
        dxx = M00 * vx + M01 * vy + M02 * vz;
        dyy = M10 * vx + M11 * vy + M12 * vz;
        dzz = M20 * vx + M21 * vy + M22 * vz;
        raylen = sqrtf(vx * vx + vy * vy + vz * vz);
    }

    const int nseg  = S - 1;
    const int ntile = (nseg + TSEG - 1) / TSEG;
    float acc0 = 0.0f, acc1 = 0.0f;

    // staged registers: pf[p] = tvals[ray = r0+4p+sub][s0 + rr]
    float pf[16];
    {
        const int idx = rr;                      // tile 0: s0 = 0
#pragma unroll
        for (int p = 0; p < 16; ++p) {
            const int ray = r0 + p * 4 + sub;
            pf[p] = (ray < R && idx < S) ? tvals[(long)ray * S + idx] : INF;
        }
    }

    for (int tl = 0; tl < ntile; ++tl) {
        // --- stage-write: regs -> LDS (compiler inserts the vmcnt wait) ---
#pragma unroll
        for (int p = 0; p < 16; ++p)
            tile[p * 4 + sub][rr] = pf[p];

        // alive predicate from staged regs (tile-start values in rr==0
        // threads): sorted + INF tail -> block-uniform break. The
        // syncthreads_count doubles as the write->read barrier.
        bool pred = false;
        if (rr == 0) {
#pragma unroll
            for (int p = 0; p < 16; ++p) pred |= (pf[p] < INF);
        }
        const int alive = __syncthreads_count(pred);
        if (alive == 0) break;

        // --- prefetch next tile into regs (issued; consumed next iter) ---
        if (tl + 1 < ntile) {
            const int idx = (tl + 1) * TSEG + rr;
#pragma unroll
            for (int p = 0; p < 16; ++p) {
                const int ray = r0 + p * 4 + sub;
                pf[p] = (ray < R && idx < S) ? tvals[(long)ray * S + idx] : INF;
            }
        }

        // --- compute: thread (rr,sub) owns cols [16*sub, 16*sub+16), in 4
        //     groups of 4: (A) offsets/weights  (B) 8 gathers back-to-back
        //     (C) accumulate. Arrays are 4-wide, fully unrolled -> registers.
        if (active) {
#pragma unroll
            for (int q = 0; q < 4; ++q) {
                float wv[4];
                int   fo[4];
                // (A) weights + clamped offsets, branchless
#pragma unroll
                for (int j = 0; j < 4; ++j) {
                    const int c = 16 * sub + q * 4 + j;
                    const bool cok = (c < TSEG);       // sub=3,q=3,j=3 -> col 63 unused
                    const float t0 = tile[rr][cok ? c : 0];
                    const float t1 = tile[rr][cok ? c + 1 : 0];
                    const bool valid = cok && (t0 < INF) && (t1 < INF) && (t1 > t0);
                    // tmid=0.5*(t0+t1); pts=a+tmid*d — separate f32 roundings,
                    // NO FMA: asm pins the product (see header comment).
                    const float tm = 0.5f * (t0 + t1);
                    float mx = tm * dxx; asm volatile("" : "+v"(mx));
                    float my = tm * dyy; asm volatile("" : "+v"(my));
                    float mz = tm * dzz; asm volatile("" : "+v"(mz));
                    const float px = ax + mx;
                    const float py = ay + my;
                    const float pz = az + mz;
                    // clamp BEFORE int cast: inf/NaN -> well-defined (proven R5)
                    const int ix = (int)floorf(fminf(fmaxf(px, -2.0f), 200.0f));
                    const int iy = (int)floorf(fminf(fmaxf(py, -2.0f), 200.0f));
                    const int iz = (int)floorf(fminf(fmaxf(pz, -2.0f), 200.0f));
                    const bool inb = ((unsigned)ix < NXv) && ((unsigned)iy < NYv) && ((unsigned)iz < NZv);
                    const int icx = min(max(ix, 0), NXv - 1);
                    const int icy = min(max(iy, 0), NYv - 1);
                    const int icz = min(max(iz, 0), NZv - 1);
                    wv[j] = (valid && inb) ? (t1 - t0) * raylen : 0.0f;
                    fo[j] = ((icx * NYv) + icy) * NZv + icz;
                }
                // (B) predicated gathers, issued back-to-back (8 in flight)
                float g0[4] = {0.f, 0.f, 0.f, 0.f};
                float g1[4] = {0.f, 0.f, 0.f, 0.f};
#pragma unroll
                for (int j = 0; j < 4; ++j) {
                    if (wv[j] > 0.0f) {              // == valid && inb (w>0 always)
                        g0[j] = vol[fo[j]];
                        if (BT > 1) g1[j] = vol[NVOX + fo[j]];
                    }
                }
                // (C) accumulate — same per-accumulator order as R8; +0 for
                //     invalid segments is bit-neutral
#pragma unroll
                for (int j = 0; j < 4; ++j) {
                    acc0 += wv[j] * g0[j];
                    if (BT > 1) acc1 += wv[j] * g1[j];
                }
            }
        }
        __syncthreads();   // tile consumed; next iter may overwrite
    }

    // --- deterministic cross-sub reduction + coalesced write ---
    red[sub][rr][0] = acc0;
    red[sub][rr][1] = (BT > 1) ? acc1 : 0.0f;
    __syncthreads();
    if (sub == 0 && active) {
        const float s0v = red[0][rr][0] + red[1][rr][0] + red[2][rr][0] + red[3][rr][0];
        out[r] = s0v;
        if (BT > 1) {
            const float s1v = red[0][rr][1] + red[1][rr][1] + red[2][rr][1] + red[3][rr][1];
            out[R + r] = s1v;
        }
    }
}

extern "C" void kernel_launch(void* const* d_in, const int* in_sizes, int n_in,
                              void* d_out, int out_size, void* d_ws, size_t ws_size,
                              hipStream_t stream) {
    const float* vol   = (const float*)d_in[0];
    const float* tvals = (const float*)d_in[1];
    const float* Mm    = (const float*)d_in[2];
    const float* bb    = (const float*)d_in[3];
    const float* src   = (const float*)d_in[4];
    const float* dst   = (const float*)d_in[5];
    float* out = (float*)d_out;

    const int R = in_sizes[5] / 3;          // rays
    const int S = in_sizes[1] / R;          // t-values per ray
    const int B = in_sizes[0] / NVOX;       // batch of volumes

    const int blocks = (R + RPB - 1) / RPB;
    dim3 grid(blocks), block(256);

    if (B == 2) {
        ct_ilp<2><<<grid, block, 0, stream>>>(vol, tvals, Mm, bb, src, dst, out, R, S);
    } else if (B == 1) {
        ct_ilp<1><<<grid, block, 0, stream>>>(vol, tvals, Mm, bb, src, dst, out, R, S);
    } else {
        int c = 0;
        for (; c + 2 <= B; c += 2)
            ct_ilp<2><<<grid, block, 0, stream>>>(vol + (long)c * NVOX, tvals, Mm, bb,
                                                  src, dst, out + (long)c * R, R, S);
        for (; c < B; ++c)
            ct_ilp<1><<<grid, block, 0, stream>>>(vol + (long)c * NVOX, tvals, Mm, bb,
                                                  src, dst, out + (long)c * R, R, S);
    }
}

// Round 12
// 82.109 us; speedup vs baseline: 1.1711x; 1.1711x over previous
//
#include <hip/hip_runtime.h>
#include <math.h>

#define NXv 128
#define NYv 128
#define NZv 128
#define NVOX (NXv * NYv * NZv)
#define RPB  64    // rays per block (lane = ray in compute phase)
#define TSEG 63    // segments per LDS tile (loads TSEG+1 = 64 t-values/ray)

// Lane-per-ray tiled kernel + reg-prefetch pipeline (exact R8 structure) +
// float2-interleaved volume in d_ws (R12).
//  * tvals bits are AUTHORITATIVE: R6 proved on-the-fly recompute differs at
//    the ulp level and flips knife-edge floors. tvals must be read.
//  * lane = ray (R7, 142->93us): adjacent rays differ only in detector v ->
//    gathers span few cache lines instead of 64 (R4/R5 130us floor).
//  * tvals coalescing via LDS transpose tile, stride 65 -> conflict-free.
//  * reg-prefetch of next tile before compute (R8, 93->84us).
//  * R9 (16-wide batch): scratch spill, 133us. R10 (balanced remap): 91us,
//    imbalance exonerated. R11 (4-wide batch): VGPR 92 -> occupancy 20%,
//    96us. LESSON: extra per-thread state trades away latency-hiding TLP.
//  * R12: the two batch volumes are 8MB apart (b-major) -> two serialized
//    gathers per segment. A one-time prep kernel interleaves them into d_ws
//    as float2; the main kernel does ONE dwordx2 gather per segment ->
//    gather chain, instruction count, and unique-line footprint all halve
//    at ZERO extra VGPR. Identical bits, identical accumulation order.
//
// NUMERICS (hard-won, rounds 1-11): x-segment midpoints land EXACTLY on
// floor() discontinuities. Golden ref is f32 numpy, SEPARATE mul-then-add.
// hipcc contracts a+tm*d into FMA -> absmax ~18.7 (threshold 1.25); __f*_rn
// are contractible (R2 == R1 bitwise); f64 mismatches (R3); recomputed t
// mismatches (R6). The asm VGPR pin on the product tm*d is what works
// (R4/R5/R7/R8/R10/R11 passed, absmax 0.0625). Do not remove.

__global__ __launch_bounds__(256) void interleave2(
    const float* __restrict__ vol, float2* __restrict__ wsv, int nvox)
{
    int i = blockIdx.x * blockDim.x + threadIdx.x;
    const int stride = gridDim.x * blockDim.x;
    for (; i < nvox; i += stride)
        wsv[i] = make_float2(vol[i], vol[nvox + i]);
}

// F2=1: gather from interleaved float2 ws volume (BT must be 2).
// F2=0: gather from the original b-major volume (any BT).
template <int BT, int F2>
__global__ __launch_bounds__(256) void ct_pipe(
    const float* __restrict__ vol,    // (B, NX, NY, NZ)
    const float2* __restrict__ wsv,   // interleaved (NVOX) float2, if F2
    const float* __restrict__ tvals,  // (R, S) sorted, +inf padded
    const float* __restrict__ Mm,     // (3,3)
    const float* __restrict__ bb,     // (3,)
    const float* __restrict__ src,    // (R,3)
    const float* __restrict__ dst,    // (R,3)
    float* __restrict__ out,          // (B, R)
    int R, int S)
{
#pragma clang fp contract(off)
    __shared__ float tile[RPB][TSEG + 2];   // 64 x 65: stride 65 -> conflict-free
    __shared__ float red[4][RPB][2];        // cross-sub reduction

    const float INF = __builtin_inff();
    const int t   = threadIdx.x;
    const int rr  = t & 63;        // compute role: ray within block
    const int sub = t >> 6;        // compute role: segment sub-range 0..3
    const int r0  = blockIdx.x * RPB;
    const int r   = r0 + rr;
    const bool active = (r < R);

    // --- per-ray geometry (verified R4/R5/R7/R8) ---
    float ax = 0, ay = 0, az = 0, dxx = 0, dyy = 0, dzz = 0, raylen = 0;
    if (active) {
        const float sx = src[r * 3 + 0], sy = src[r * 3 + 1], sz = src[r * 3 + 2];
        const float ex = dst[r * 3 + 0], ey = dst[r * 3 + 1], ez = dst[r * 3 + 2];
        const float M00 = Mm[0], M01 = Mm[1], M02 = Mm[2];
        const float M10 = Mm[3], M11 = Mm[4], M12 = Mm[5];
        const float M20 = Mm[6], M21 = Mm[7], M22 = Mm[8];
        ax = M00 * sx + M01 * sy + M02 * sz + bb[0];
        ay = M10 * sx + M11 * sy + M12 * sz + bb[1];
        az = M20 * sx + M21 * sy + M22 * sz + bb[2];
        const float vx = ex - sx, vy = ey - sy, vz = ez - sz;
        dxx = M00 * vx + M01 * vy + M02 * vz;
        dyy = M10 * vx + M11 * vy + M12 * vz;
        dzz = M20 * vx + M21 * vy + M22 * vz;
        raylen = sqrtf(vx * vx + vy * vy + vz * vz);
    }

    const int nseg  = S - 1;
    const int ntile = (nseg + TSEG - 1) / TSEG;
    float acc0 = 0.0f, acc1 = 0.0f;

    // staged registers: pf[p] = tvals[ray = r0+4p+sub][s0 + rr]
    float pf[16];
    {
        const int idx = rr;                      // tile 0: s0 = 0
#pragma unroll
        for (int p = 0; p < 16; ++p) {
            const int ray = r0 + p * 4 + sub;
            pf[p] = (ray < R && idx < S) ? tvals[(long)ray * S + idx] : INF;
        }
    }

    for (int tl = 0; tl < ntile; ++tl) {
        // --- stage-write: regs -> LDS (compiler inserts the vmcnt wait) ---
#pragma unroll
        for (int p = 0; p < 16; ++p)
            tile[p * 4 + sub][rr] = pf[p];

        // alive predicate from staged regs (tile-start values in rr==0
        // threads): sorted + INF tail -> block-uniform break. The
        // syncthreads_count doubles as the write->read barrier.
        bool pred = false;
        if (rr == 0) {
#pragma unroll
            for (int p = 0; p < 16; ++p) pred |= (pf[p] < INF);
        }
        const int alive = __syncthreads_count(pred);
        if (alive == 0) break;

        // --- prefetch next tile into regs (issued; consumed next iter) ---
        if (tl + 1 < ntile) {
            const int idx = (tl + 1) * TSEG + rr;
#pragma unroll
            for (int p = 0; p < 16; ++p) {
                const int ray = r0 + p * 4 + sub;
                pf[p] = (ray < R && idx < S) ? tvals[(long)ray * S + idx] : INF;
            }
        }

        // --- compute: thread (rr,sub) owns cols [16*sub, 16*sub+16), fully
        //     unrolled; s>=nseg needs no check (INF padding -> invalid) ---
        if (active) {
#pragma unroll
            for (int j = 0; j < 16; ++j) {
                const int c = 16 * sub + j;
                if (c < TSEG) {
                    const float t0 = tile[rr][c];
                    const float t1 = tile[rr][c + 1];
                    if ((t0 < INF) && (t1 < INF) && (t1 > t0)) {
                        // tmid=0.5*(t0+t1); pts=a+tmid*d — separate f32
                        // roundings, NO FMA: asm pins the product.
                        const float tm = 0.5f * (t0 + t1);
                        float mx = tm * dxx; asm volatile("" : "+v"(mx));
                        float my = tm * dyy; asm volatile("" : "+v"(my));
                        float mz = tm * dzz; asm volatile("" : "+v"(mz));
                        const float px = ax + mx;
                        const float py = ay + my;
                        const float pz = az + mz;
                        const int ix = (int)floorf(px);
                        const int iy = (int)floorf(py);
                        const int iz = (int)floorf(pz);
                        if ((unsigned)ix < NXv && (unsigned)iy < NYv && (unsigned)iz < NZv) {
                            const float w = (t1 - t0) * raylen;
                            const int flat = ((ix * NYv) + iy) * NZv + iz;
                            if (F2) {
                                const float2 g = wsv[flat];   // one dwordx2
                                acc0 += w * g.x;
                                acc1 += w * g.y;
                            } else {
                                acc0 += w * vol[flat];
                                if (BT > 1) acc1 += w * vol[NVOX + flat];
                            }
                        }
                    }
                }
            }
        }
        __syncthreads();   // tile consumed; next iter may overwrite
    }

    // --- deterministic cross-sub reduction + coalesced write ---
    red[sub][rr][0] = acc0;
    red[sub][rr][1] = (BT > 1) ? acc1 : 0.0f;
    __syncthreads();
    if (sub == 0 && active) {
        const float s0v = red[0][rr][0] + red[1][rr][0] + red[2][rr][0] + red[3][rr][0];
        out[r] = s0v;
        if (BT > 1) {
            const float s1v = red[0][rr][1] + red[1][rr][1] + red[2][rr][1] + red[3][rr][1];
            out[R + r] = s1v;
        }
    }
}

extern "C" void kernel_launch(void* const* d_in, const int* in_sizes, int n_in,
                              void* d_out, int out_size, void* d_ws, size_t ws_size,
                              hipStream_t stream) {
    const float* vol   = (const float*)d_in[0];
    const float* tvals = (const float*)d_in[1];
    const float* Mm    = (const float*)d_in[2];
    const float* bb    = (const float*)d_in[3];
    const float* src   = (const float*)d_in[4];
    const float* dst   = (const float*)d_in[5];
    float* out = (float*)d_out;

    const int R = in_sizes[5] / 3;          // rays
    const int S = in_sizes[1] / R;          // t-values per ray
    const int B = in_sizes[0] / NVOX;       // batch of volumes

    const int blocks = (R + RPB - 1) / RPB;
    dim3 grid(blocks), block(256);

    const size_t need = (size_t)NVOX * sizeof(float2);

    if (B == 2 && ws_size >= need) {
        // one-time interleave: ws[i] = (vol0[i], vol1[i])
        float2* wsv = (float2*)d_ws;
        interleave2<<<2048, 256, 0, stream>>>(vol, wsv, NVOX);
        ct_pipe<2, 1><<<grid, block, 0, stream>>>(vol, wsv, tvals, Mm, bb, src, dst, out, R, S);
    } else if (B == 2) {
        ct_pipe<2, 0><<<grid, block, 0, stream>>>(vol, nullptr, tvals, Mm, bb, src, dst, out, R, S);
    } else if (B == 1) {
        ct_pipe<1, 0><<<grid, block, 0, stream>>>(vol, nullptr, tvals, Mm, bb, src, dst, out, R, S);
    } else {
        int c = 0;
        for (; c + 2 <= B; c += 2)
            ct_pipe<2, 0><<<grid, block, 0, stream>>>(vol + (long)c * NVOX, nullptr, tvals, Mm, bb,
                                                      src, dst, out + (long)c * R, R, S);
        for (; c < B; ++c)
            ct_pipe<1, 0><<<grid, block, 0, stream>>>(vol + (long)c * NVOX, nullptr, tvals, Mm, bb,
                                                      src, dst, out + (long)c * R, R, S);
    }
}

// Round 13
// 82.097 us; speedup vs baseline: 1.1713x; 1.0001x over previous
//
#include <hip/hip_runtime.h>
#include <math.h>

#define NXv 128
#define NYv 128
#define NZv 128
#define NVOX (NXv * NYv * NZv)
#define RPB  64    // rays per block (lane = ray in compute phase)
#define TSEG 63    // segments per LDS tile (loads TSEG+1 = 64 t-values/ray)

// Lane-per-ray tiled kernel + reg-prefetch pipeline + float2 volume +
// XCD-aware balanced block swizzle (R13).
//  * tvals bits are AUTHORITATIVE (R6): must be read, not recomputed.
//  * lane = ray (R7, 142->93us): gathers span few cache lines, not 64.
//  * tvals coalescing via LDS transpose tile, stride 65 -> conflict-free.
//  * reg-prefetch of next tile before compute (R8, 93->84us).
//  * float2-interleaved volume in d_ws (R12, 84->82us): 1 gather/segment.
//  * R9 16-wide batch: spill, 133us. R10 ray remap: 91us. R11 4-wide batch:
//    VGPR 92 -> occupancy 20%, 96us. LESSON: per-thread state kills TLP.
//  * R13: VALU accounting proves ~75% of cycles are gather-latency stalls.
//    Default dispatch gives each XCD's 256 resident blocks the WHOLE 16MB
//    volume through its private 4MB L2 (thrash -> L3 latency). Swizzle
//    chunk=128: XCD k runs blocks [128k,128k+128) u [1024+128k, ...+128) —
//    two ~1MB beam wedges, symmetric about u=0 (|u|+|u +- half| ~= 128 ->
//    per-XCD work constant). Gathers become L2 hits.
//
// NUMERICS (hard-won, rounds 1-12): x-segment midpoints land EXACTLY on
// floor() discontinuities. Golden ref is f32 numpy, SEPARATE mul-then-add.
// hipcc contracts a+tm*d into FMA -> absmax ~18.7 (threshold 1.25); __f*_rn
// are contractible (R2 == R1 bitwise); f64 mismatches (R3); recomputed t
// mismatches (R6). The asm VGPR pin on the product tm*d is what works
// (R4/R5/R7/R8/R10/R11/R12 passed, absmax 0.0625). Do not remove.

__global__ __launch_bounds__(256) void interleave2(
    const float* __restrict__ vol, float2* __restrict__ wsv, int nvox)
{
    int i = blockIdx.x * blockDim.x + threadIdx.x;
    const int stride = gridDim.x * blockDim.x;
    for (; i < nvox; i += stride)
        wsv[i] = make_float2(vol[i], vol[nvox + i]);
}

// F2=1: gather from interleaved float2 ws volume (BT must be 2).
// F2=0: gather from the original b-major volume (any BT).
template <int BT, int F2>
__global__ __launch_bounds__(256) void ct_pipe(
    const float* __restrict__ vol,    // (B, NX, NY, NZ)
    const float2* __restrict__ wsv,   // interleaved (NVOX) float2, if F2
    const float* __restrict__ tvals,  // (R, S) sorted, +inf padded
    const float* __restrict__ Mm,     // (3,3)
    const float* __restrict__ bb,     // (3,)
    const float* __restrict__ src,    // (R,3)
    const float* __restrict__ dst,    // (R,3)
    float* __restrict__ out,          // (B, R)
    int R, int S, int swz)
{
#pragma clang fp contract(off)
    __shared__ float tile[RPB][TSEG + 2];   // 64 x 65: stride 65 -> conflict-free
    __shared__ float red[4][RPB][2];        // cross-sub reduction

    const float INF = __builtin_inff();
    const int t   = threadIdx.x;
    const int rr  = t & 63;        // compute role: ray within block
    const int sub = t >> 6;        // compute role: segment sub-range 0..3

    // --- XCD-aware balanced swizzle (bijective for grid = 2048) ---
    // scheduled index i -> original block b: XCD k = i&7 runs original
    // chunks k and k+8 (chunk = 128 blocks = 32 u-strips ~ 1MB wedge).
    int b = blockIdx.x;
    if (swz) {
        const int k = b & 7;
        const int j = b >> 3;                 // 0..255
        b = k * 128 + (j & 127) + (j >> 7) * 1024;
    }
    const int r0  = b * RPB;
    const int r   = r0 + rr;
    const bool active = (r < R);

    // --- per-ray geometry (verified R4/R5/R7/R8) ---
    float ax = 0, ay = 0, az = 0, dxx = 0, dyy = 0, dzz = 0, raylen = 0;
    if (active) {
        const float sx = src[r * 3 + 0], sy = src[r * 3 + 1], sz = src[r * 3 + 2];
        const float ex = dst[r * 3 + 0], ey = dst[r * 3 + 1], ez = dst[r * 3 + 2];
        const float M00 = Mm[0], M01 = Mm[1], M02 = Mm[2];
        const float M10 = Mm[3], M11 = Mm[4], M12 = Mm[5];
        const float M20 = Mm[6], M21 = Mm[7], M22 = Mm[8];
        ax = M00 * sx + M01 * sy + M02 * sz + bb[0];
        ay = M10 * sx + M11 * sy + M12 * sz + bb[1];
        az = M20 * sx + M21 * sy + M22 * sz + bb[2];
        const float vx = ex - sx, vy = ey - sy, vz = ez - sz;
        dxx = M00 * vx + M01 * vy + M02 * vz;
        dyy = M10 * vx + M11 * vy + M12 * vz;
        dzz = M20 * vx + M21 * vy + M22 * vz;
        raylen = sqrtf(vx * vx + vy * vy + vz * vz);
    }

    const int nseg  = S - 1;
    const int ntile = (nseg + TSEG - 1) / TSEG;
    float acc0 = 0.0f, acc1 = 0.0f;

    // staged registers: pf[p] = tvals[ray = r0+4p+sub][s0 + rr]
    float pf[16];
    {
        const int idx = rr;                      // tile 0: s0 = 0
#pragma unroll
        for (int p = 0; p < 16; ++p) {
            const int ray = r0 + p * 4 + sub;
            pf[p] = (ray < R && idx < S) ? tvals[(long)ray * S + idx] : INF;
        }
    }

    for (int tl = 0; tl < ntile; ++tl) {
        // --- stage-write: regs -> LDS (compiler inserts the vmcnt wait) ---
#pragma unroll
        for (int p = 0; p < 16; ++p)
            tile[p * 4 + sub][rr] = pf[p];

        // alive predicate from staged regs (tile-start values in rr==0
        // threads): sorted + INF tail -> block-uniform break. The
        // syncthreads_count doubles as the write->read barrier.
        bool pred = false;
        if (rr == 0) {
#pragma unroll
            for (int p = 0; p < 16; ++p) pred |= (pf[p] < INF);
        }
        const int alive = __syncthreads_count(pred);
        if (alive == 0) break;

        // --- prefetch next tile into regs (issued; consumed next iter) ---
        if (tl + 1 < ntile) {
            const int idx = (tl + 1) * TSEG + rr;
#pragma unroll
            for (int p = 0; p < 16; ++p) {
                const int ray = r0 + p * 4 + sub;
                pf[p] = (ray < R && idx < S) ? tvals[(long)ray * S + idx] : INF;
            }
        }

        // --- compute: thread (rr,sub) owns cols [16*sub, 16*sub+16), fully
        //     unrolled; s>=nseg needs no check (INF padding -> invalid) ---
        if (active) {
#pragma unroll
            for (int j = 0; j < 16; ++j) {
                const int c = 16 * sub + j;
                if (c < TSEG) {
                    const float t0 = tile[rr][c];
                    const float t1 = tile[rr][c + 1];
                    if ((t0 < INF) && (t1 < INF) && (t1 > t0)) {
                        // tmid=0.5*(t0+t1); pts=a+tmid*d — separate f32
                        // roundings, NO FMA: asm pins the product.
                        const float tm = 0.5f * (t0 + t1);
                        float mx = tm * dxx; asm volatile("" : "+v"(mx));
                        float my = tm * dyy; asm volatile("" : "+v"(my));
                        float mz = tm * dzz; asm volatile("" : "+v"(mz));
                        const float px = ax + mx;
                        const float py = ay + my;
                        const float pz = az + mz;
                        const int ix = (int)floorf(px);
                        const int iy = (int)floorf(py);
                        const int iz = (int)floorf(pz);
                        if ((unsigned)ix < NXv && (unsigned)iy < NYv && (unsigned)iz < NZv) {
                            const float w = (t1 - t0) * raylen;
                            const int flat = ((ix * NYv) + iy) * NZv + iz;
                            if (F2) {
                                const float2 g = wsv[flat];   // one dwordx2
                                acc0 += w * g.x;
                                acc1 += w * g.y;
                            } else {
                                acc0 += w * vol[flat];
                                if (BT > 1) acc1 += w * vol[NVOX + flat];
                            }
                        }
                    }
                }
            }
        }
        __syncthreads();   // tile consumed; next iter may overwrite
    }

    // --- deterministic cross-sub reduction + coalesced write ---
    red[sub][rr][0] = acc0;
    red[sub][rr][1] = (BT > 1) ? acc1 : 0.0f;
    __syncthreads();
    if (sub == 0 && active) {
        const float s0v = red[0][rr][0] + red[1][rr][0] + red[2][rr][0] + red[3][rr][0];
        out[r] = s0v;
        if (BT > 1) {
            const float s1v = red[0][rr][1] + red[1][rr][1] + red[2][rr][1] + red[3][rr][1];
            out[R + r] = s1v;
        }
    }
}

extern "C" void kernel_launch(void* const* d_in, const int* in_sizes, int n_in,
                              void* d_out, int out_size, void* d_ws, size_t ws_size,
                              hipStream_t stream) {
    const float* vol   = (const float*)d_in[0];
    const float* tvals = (const float*)d_in[1];
    const float* Mm    = (const float*)d_in[2];
    const float* bb    = (const float*)d_in[3];
    const float* src   = (const float*)d_in[4];
    const float* dst   = (const float*)d_in[5];
    float* out = (float*)d_out;

    const int R = in_sizes[5] / 3;          // rays
    const int S = in_sizes[1] / R;          // t-values per ray
    const int B = in_sizes[0] / NVOX;       // batch of volumes

    const int blocks = (R + RPB - 1) / RPB;
    dim3 grid(blocks), block(256);

    // swizzle mapping is specific to grid == 2048 (detector 512x256)
    const int swz = (blocks == 2048) ? 1 : 0;

    const size_t need = (size_t)NVOX * sizeof(float2);

    if (B == 2 && ws_size >= need) {
        // one-time interleave: ws[i] = (vol0[i], vol1[i])
        float2* wsv = (float2*)d_ws;
        interleave2<<<2048, 256, 0, stream>>>(vol, wsv, NVOX);
        ct_pipe<2, 1><<<grid, block, 0, stream>>>(vol, wsv, tvals, Mm, bb, src, dst, out, R, S, swz);
    } else if (B == 2) {
        ct_pipe<2, 0><<<grid, block, 0, stream>>>(vol, nullptr, tvals, Mm, bb, src, dst, out, R, S, swz);
    } else if (B == 1) {
        ct_pipe<1, 0><<<grid, block, 0, stream>>>(vol, nullptr, tvals, Mm, bb, src, dst, out, R, S, swz);
    } else {
        int c = 0;
        for (; c + 2 <= B; c += 2)
            ct_pipe<2, 0><<<grid, block, 0, stream>>>(vol + (long)c * NVOX, nullptr, tvals, Mm, bb,
                                                      src, dst, out + (long)c * R, R, S, swz);
        for (; c < B; ++c)
            ct_pipe<1, 0><<<grid, block, 0, stream>>>(vol + (long)c * NVOX, nullptr, tvals, Mm, bb,
                                                      src, dst, out + (long)c * R, R, S, swz);
    }
}

// Round 14
// 64.190 us; speedup vs baseline: 1.4980x; 1.2790x over previous
//
#include <hip/hip_runtime.h>
#include <math.h>

#define NXv 128
#define NYv 128
#define NZv 128
#define NVOX (NXv * NYv * NZv)
#define RPB  32    // rays per block (32 rays x 8 subs = 256 threads)
#define NSUB 8     // segment sub-ranges per ray
#define TSEG 63    // segments per LDS tile (loads TSEG+1 = 64 t-values/ray)

// Lane-per-ray tiled kernel + reg-prefetch pipeline + float2 volume +
// 2x-oversubscribed grid for tail refill (R14).
//  * tvals bits are AUTHORITATIVE (R6): must be read, not recomputed.
//  * lane = ray (R7, 142->93us): gathers span few cache lines, not 64.
//  * tvals coalescing via LDS transpose tile, stride 65 -> conflict-free.
//  * reg-prefetch of next tile before compute (R8, 93->84us).
//  * float2-interleaved volume in d_ws (R12, 84->82us): 1 gather/segment.
//  * R9/R11 wide batches: VGPR/occupancy loss. R10 lane-mixing balance:
//    wave = max(lanes) -> useless. R13 XCD swizzle: neutral (L2 exonerated).
//  * R14: R8-R13 all had grid == EXACTLY one residency round (524288
//    threads == 2048/CU capacity) -> retired blocks never refill; kernel
//    dur ~= slowest block (~2x mean); Occupancy 42% == avg/max work. Fix:
//    32 rays x 8 subs per block -> 2x total threads -> grid 4096 = two
//    rounds -> refill amortizes the tail. Also: per-thread gather chain
//    halves (8 segs), pf[16]->pf[8], LDS 18.9->10.3KB.
//
// NUMERICS (hard-won, rounds 1-13): x-segment midpoints land EXACTLY on
// floor() discontinuities. Golden ref is f32 numpy, SEPARATE mul-then-add.
// hipcc contracts a+tm*d into FMA -> absmax ~18.7 (threshold 1.25); __f*_rn
// are contractible (R2 == R1 bitwise); f64 mismatches (R3); recomputed t
// mismatches (R6). The asm VGPR pin on the product tm*d is what works
// (R4/R5/R7/R8/R10-R13 passed, absmax 0.0625). Do not remove.

__global__ __launch_bounds__(256) void interleave2(
    const float* __restrict__ vol, float2* __restrict__ wsv, int nvox)
{
    int i = blockIdx.x * blockDim.x + threadIdx.x;
    const int stride = gridDim.x * blockDim.x;
    for (; i < nvox; i += stride)
        wsv[i] = make_float2(vol[i], vol[nvox + i]);
}

// F2=1: gather from interleaved float2 ws volume (BT must be 2).
// F2=0: gather from the original b-major volume (any BT).
template <int BT, int F2>
__global__ __launch_bounds__(256) void ct_pipe(
    const float* __restrict__ vol,    // (B, NX, NY, NZ)
    const float2* __restrict__ wsv,   // interleaved (NVOX) float2, if F2
    const float* __restrict__ tvals,  // (R, S) sorted, +inf padded
    const float* __restrict__ Mm,     // (3,3)
    const float* __restrict__ bb,     // (3,)
    const float* __restrict__ src,    // (R,3)
    const float* __restrict__ dst,    // (R,3)
    float* __restrict__ out,          // (B, R)
    int R, int S)
{
#pragma clang fp contract(off)
    __shared__ float tile[RPB][TSEG + 2];     // 32 x 65: stride 65 -> conflict-free
    __shared__ float red[NSUB][RPB][2];       // cross-sub reduction

    const float INF = __builtin_inff();
    const int t    = threadIdx.x;
    const int rr   = t & (RPB - 1);   // compute role: ray within block (0..31)
    const int sub  = t >> 5;          // compute role: segment sub-range (0..7)
    const int w    = t >> 6;          // wave index (0..3), for load mapping
    const int lane = t & 63;          // lane within wave, for load mapping
    const int r0   = blockIdx.x * RPB;
    const int r    = r0 + rr;
    const bool active = (r < R);

    // --- per-ray geometry (verified R4/R5/R7/R8) ---
    float ax = 0, ay = 0, az = 0, dxx = 0, dyy = 0, dzz = 0, raylen = 0;
    if (active) {
        const float sx = src[r * 3 + 0], sy = src[r * 3 + 1], sz = src[r * 3 + 2];
        const float ex = dst[r * 3 + 0], ey = dst[r * 3 + 1], ez = dst[r * 3 + 2];
        const float M00 = Mm[0], M01 = Mm[1], M02 = Mm[2];
        const float M10 = Mm[3], M11 = Mm[4], M12 = Mm[5];
        const float M20 = Mm[6], M21 = Mm[7], M22 = Mm[8];
        ax = M00 * sx + M01 * sy + M02 * sz + bb[0];
        ay = M10 * sx + M11 * sy + M12 * sz + bb[1];
        az = M20 * sx + M21 * sy + M22 * sz + bb[2];
        const float vx = ex - sx, vy = ey - sy, vz = ez - sz;
        dxx = M00 * vx + M01 * vy + M02 * vz;
        dyy = M10 * vx + M11 * vy + M12 * vz;
        dzz = M20 * vx + M21 * vy + M22 * vz;
        raylen = sqrtf(vx * vx + vy * vy + vz * vz);
    }

    const int nseg  = S - 1;
    const int ntile = (nseg + TSEG - 1) / TSEG;
    float acc0 = 0.0f, acc1 = 0.0f;

    // staged registers: pf[p] = tvals[ray = r0 + 4p + w][s0 + lane]
    // (wave reads 64 consecutive t-values of one ray per pass -> coalesced)
    float pf[8];
    {
#pragma unroll
        for (int p = 0; p < 8; ++p) {
            const int ray = r0 + p * 4 + w;
            pf[p] = (ray < R && lane < S) ? tvals[(long)ray * S + lane] : INF;
        }
    }

    for (int tl = 0; tl < ntile; ++tl) {
        // --- stage-write: regs -> LDS (compiler inserts the vmcnt wait) ---
#pragma unroll
        for (int p = 0; p < 8; ++p)
            tile[p * 4 + w][lane] = pf[p];

        // alive predicate from staged regs: lane-0 threads (w=0..3) hold the
        // tile-start value of rays p*4+w (p=0..7) -> union covers all 32
        // rays. Sorted + INF tail -> block-uniform break. The
        // syncthreads_count doubles as the write->read barrier.
        bool pred = false;
        if (lane == 0) {
#pragma unroll
            for (int p = 0; p < 8; ++p) pred |= (pf[p] < INF);
        }
        const int alive = __syncthreads_count(pred);
        if (alive == 0) break;

        // --- prefetch next tile into regs (issued; consumed next iter) ---
        if (tl + 1 < ntile) {
            const int idx = (tl + 1) * TSEG + lane;
#pragma unroll
            for (int p = 0; p < 8; ++p) {
                const int ray = r0 + p * 4 + w;
                pf[p] = (ray < R && idx < S) ? tvals[(long)ray * S + idx] : INF;
            }
        }

        // --- compute: thread (rr,sub) owns cols [8*sub, 8*sub+8), fully
        //     unrolled; col 63 excluded (c < TSEG); INF padding handles
        //     segments past nseg ---
        if (active) {
#pragma unroll
            for (int j = 0; j < 8; ++j) {
                const int c = 8 * sub + j;
                if (c < TSEG) {
                    const float t0 = tile[rr][c];
                    const float t1 = tile[rr][c + 1];
                    if ((t0 < INF) && (t1 < INF) && (t1 > t0)) {
                        // tmid=0.5*(t0+t1); pts=a+tmid*d — separate f32
                        // roundings, NO FMA: asm pins the product.
                        const float tm = 0.5f * (t0 + t1);
                        float mx = tm * dxx; asm volatile("" : "+v"(mx));
                        float my = tm * dyy; asm volatile("" : "+v"(my));
                        float mz = tm * dzz; asm volatile("" : "+v"(mz));
                        const float px = ax + mx;
                        const float py = ay + my;
                        const float pz = az + mz;
                        const int ix = (int)floorf(px);
                        const int iy = (int)floorf(py);
                        const int iz = (int)floorf(pz);
                        if ((unsigned)ix < NXv && (unsigned)iy < NYv && (unsigned)iz < NZv) {
                            const float w_ = (t1 - t0) * raylen;
                            const int flat = ((ix * NYv) + iy) * NZv + iz;
                            if (F2) {
                                const float2 g = wsv[flat];   // one dwordx2
                                acc0 += w_ * g.x;
                                acc1 += w_ * g.y;
                            } else {
                                acc0 += w_ * vol[flat];
                                if (BT > 1) acc1 += w_ * vol[NVOX + flat];
                            }
                        }
                    }
                }
            }
        }
        __syncthreads();   // tile consumed; next iter may overwrite
    }

    // --- deterministic cross-sub reduction + coalesced write ---
    red[sub][rr][0] = acc0;
    red[sub][rr][1] = (BT > 1) ? acc1 : 0.0f;
    __syncthreads();
    if (sub == 0 && active) {
        float s0v = 0.0f, s1v = 0.0f;
#pragma unroll
        for (int p = 0; p < NSUB; ++p) s0v += red[p][rr][0];
        out[r] = s0v;
        if (BT > 1) {
#pragma unroll
            for (int p = 0; p < NSUB; ++p) s1v += red[p][rr][1];
            out[R + r] = s1v;
        }
    }
}

extern "C" void kernel_launch(void* const* d_in, const int* in_sizes, int n_in,
                              void* d_out, int out_size, void* d_ws, size_t ws_size,
                              hipStream_t stream) {
    const float* vol   = (const float*)d_in[0];
    const float* tvals = (const float*)d_in[1];
    const float* Mm    = (const float*)d_in[2];
    const float* bb    = (const float*)d_in[3];
    const float* src   = (const float*)d_in[4];
    const float* dst   = (const float*)d_in[5];
    float* out = (float*)d_out;

    const int R = in_sizes[5] / 3;          // rays
    const int S = in_sizes[1] / R;          // t-values per ray
    const int B = in_sizes[0] / NVOX;       // batch of volumes

    const int blocks = (R + RPB - 1) / RPB; // 4096 for R=131072
    dim3 grid(blocks), block(RPB * NSUB);   // 256 threads

    const size_t need = (size_t)NVOX * sizeof(float2);

    if (B == 2 && ws_size >= need) {
        // one-time interleave: ws[i] = (vol0[i], vol1[i])
        float2* wsv = (float2*)d_ws;
        interleave2<<<2048, 256, 0, stream>>>(vol, wsv, NVOX);
        ct_pipe<2, 1><<<grid, block, 0, stream>>>(vol, wsv, tvals, Mm, bb, src, dst, out, R, S);
    } else if (B == 2) {
        ct_pipe<2, 0><<<grid, block, 0, stream>>>(vol, nullptr, tvals, Mm, bb, src, dst, out, R, S);
    } else if (B == 1) {
        ct_pipe<1, 0><<<grid, block, 0, stream>>>(vol, nullptr, tvals, Mm, bb, src, dst, out, R, S);
    } else {
        int c = 0;
        for (; c + 2 <= B; c += 2)
            ct_pipe<2, 0><<<grid, block, 0, stream>>>(vol + (long)c * NVOX, nullptr, tvals, Mm, bb,
                                                      src, dst, out + (long)c * R, R, S);
        for (; c < B; ++c)
            ct_pipe<1, 0><<<grid, block, 0, stream>>>(vol + (long)c * NVOX, nullptr, tvals, Mm, bb,
                                                      src, dst, out + (long)c * R, R, S);
    }
}